// Round 3
// baseline (144.037 us; speedup 1.0000x reference)
//
#include <hip/hip_runtime.h>
#include <hip/hip_bf16.h>
#include <cstdint>

typedef __attribute__((ext_vector_type(8))) short  short8;   // 8 x bf16 (4 VGPR)
typedef __attribute__((ext_vector_type(4))) float  f32x4;
typedef __attribute__((ext_vector_type(4))) unsigned uint4v;

#define N_ROWS   4096
#define IN_DIM   256
#define OUT_DIM  256
#define K_TOTAL  16384      // IN_DIM * GRIDSZ * 2
#define SPLITK   8
#define KCHUNK   2048       // K_TOTAL / SPLITK
#define BM       128
#define BN       128
#define BK       64
#define STEPS    32         // KCHUNK / BK == #i handled per block

// ---------------------------------------------------------------------------
// BmatT[j][k] (bf16), k = i*64 + g*2 + p ; p=0 -> cos coeffs, p=1 -> sin.
// coeffs layout: [2][out][in][grid] fp32.
__global__ void convert_coeffs(const float* __restrict__ w,
                               __hip_bfloat16* __restrict__ bm) {
    int gid = blockIdx.x * 256 + threadIdx.x;      // 0 .. 256*16384-1
    int j = gid >> 14;
    int k = gid & (K_TOTAL - 1);
    int i = k >> 6;
    int r = k & 63;
    int g = r >> 1;
    int p = r & 1;
    float v = w[(((p << 8) + j) * 256 + i) * 32 + g];
    bm[gid] = __float2bfloat16(v);
}

__global__ void bias_fill(const float* __restrict__ bias, float* __restrict__ out) {
    int gid = blockIdx.x * 256 + threadIdx.x;
    out[gid] = bias[gid & (OUT_DIM - 1)];
}

// ---------------------------------------------------------------------------
__device__ __forceinline__ void gld_lds16(const void* g, void* l) {
    // dest is wave-uniform base; HW writes lane*16B.
    __builtin_amdgcn_global_load_lds(
        (const __attribute__((address_space(1))) void*)(uintptr_t)g,
        (__attribute__((address_space(3))) void*)(uintptr_t)l, 16, 0, 0);
}

// round-to-nearest-even f32 -> bf16 (non-NaN inputs), returned in low 16 bits
__device__ __forceinline__ unsigned f2bf(float f) {
    unsigned u = __builtin_bit_cast(unsigned, f);
    return (u + 0x7fffu + ((u >> 16) & 1u)) >> 16;
}

// 256 threads = 4 waves (2x2), wave tile 64x64. LDS 64 KiB -> 2 blocks/CU.
__global__ __launch_bounds__(256, 2) void fkan_gemm(const float* __restrict__ x,
                                                    const __hip_bfloat16* __restrict__ bm,
                                                    float* __restrict__ out) {
    __shared__ float  x_lds[STEPS][BM];    // 16 KiB, transposed: [i_local][m]
    __shared__ short  A_lds[BM * BK];      // 16 KiB, single-buffered, XOR-swizzled
    __shared__ short  B_lds[2][BN * BK];   // 32 KiB, dbuf, swizzle via global src perm

    const int tid  = threadIdx.x;
    const int lane = tid & 63;
    const int wid  = tid >> 6;      // 4 waves
    const int wm   = wid >> 1;      // 0..1 -> 64-row slice
    const int wn   = wid & 1;       // 0..1 -> 64-col slice

    const int bid = blockIdx.x;
    const int ks  = bid & 7;        // k-split; same-ks blocks share an XCD's L2
    const int tt  = bid >> 3;
    const int mb  = tt >> 1;
    const int nb  = tt & 1;
    const int m0  = mb * BM;
    const int n0  = nb * BN;
    const int i0  = ks * STEPS;
    const int kbase = ks * KCHUNK;

    auto stage_B = [&](int s, int buf) {
        int kg = kbase + s * BK;
        #pragma unroll
        for (int r = 0; r < 4; ++r) {
            int jl = wid * 32 + r * 8 + (lane >> 3);     // LDS row this lane fills
            int cg = (lane & 7) ^ (jl & 7);              // inverse-swizzled src chunk
            const __hip_bfloat16* src = bm + (size_t)(n0 + jl) * K_TOTAL + kg + cg * 8;
            gld_lds16(src, &B_lds[buf][(wid * 32 + r * 8) * BK]);
        }
    };

    const int am = tid & 127;   // A-gen: row this thread generates
    const int ah = tid >> 7;    // A-gen: half (16 multipliers each)

    auto gen_A = [&](int s) {
        float xv = x_lds[s][am];
        float c1, s1; __sincosf(xv, &s1, &c1);                          // cis(x)
        float cg, sg; __sincosf((float)(16 * ah + 1) * xv, &sg, &cg);   // cis((16h+1)x)
        unsigned pk[16];
        #pragma unroll
        for (int e = 0; e < 16; ++e) {
            pk[e] = f2bf(cg) | (f2bf(sg) << 16);         // even k=cos, odd k=sin
            float cn = cg * c1 - sg * s1;                // cis((g+1)x)=cis(gx)cis(x)
            sg = sg * c1 + cg * s1;
            cg = cn;
        }
        int base = am * BK;
        #pragma unroll
        for (int q = 0; q < 4; ++q) {
            uint4v w = {pk[4 * q], pk[4 * q + 1], pk[4 * q + 2], pk[4 * q + 3]};
            *(uint4v*)&A_lds[base + (((4 * ah + q) ^ (am & 7)) << 3)] = w;
        }
    };

    f32x4 acc[4][4];
    #pragma unroll
    for (int a = 0; a < 4; ++a)
        #pragma unroll
        for (int b = 0; b < 4; ++b) acc[a][b] = (f32x4){0.f, 0.f, 0.f, 0.f};

    auto compute = [&](int buf) {
        const int rA = lane & 15;
        const int cA = lane >> 4;
        #pragma unroll
        for (int kf = 0; kf < 2; ++kf) {
            short8 af[4], bf[4];
            #pragma unroll
            for (int mf = 0; mf < 4; ++mf) {
                int row = wm * 64 + mf * 16 + rA;
                int ch  = (kf * 4 + cA) ^ (rA & 7);
                af[mf] = *(const short8*)&A_lds[row * BK + ch * 8];
            }
            #pragma unroll
            for (int nf = 0; nf < 4; ++nf) {
                int row = wn * 64 + nf * 16 + rA;
                int ch  = (kf * 4 + cA) ^ (rA & 7);
                bf[nf] = *(const short8*)&B_lds[buf][row * BK + ch * 8];
            }
            #pragma unroll
            for (int mf = 0; mf < 4; ++mf)
                #pragma unroll
                for (int nf = 0; nf < 4; ++nf)
                    acc[mf][nf] = __builtin_amdgcn_mfma_f32_16x16x32_bf16(
                        af[mf], bf[nf], acc[mf][nf], 0, 0, 0);
        }
    };

    // ---- prologue: issue B(0), stage x panel, gen A(0) ----
    stage_B(0, 0);
    #pragma unroll
    for (int s2 = 0; s2 < 4; ++s2) {
        int slot = tid + s2 * 256;              // 1024 float4 slots
        int m  = slot >> 3;
        int c4 = slot & 7;
        f32x4 xv = *(const f32x4*)&x[(size_t)(m0 + m) * IN_DIM + i0 + c4 * 4];
        #pragma unroll
        for (int q = 0; q < 4; ++q) x_lds[c4 * 4 + q][m] = xv[q];
    }
    __syncthreads();        // x visible (also drains B(0) DMA)
    gen_A(0);

    int cur = 0;
    for (int s = 0; s < STEPS; ++s) {
        __syncthreads();                                // A[s] written, B[cur] landed
        if (s + 1 < STEPS) stage_B(s + 1, cur ^ 1);     // issue early, drains next iter
        compute(cur);
        __syncthreads();                                // all waves done reading A[s]
        if (s + 1 < STEPS) gen_A(s + 1);
        cur ^= 1;
    }

    // epilogue: C/D layout col=lane&15, row=(lane>>4)*4+reg (m89-verified)
    const int cl = lane & 15;
    const int rl = (lane >> 4) * 4;
    #pragma unroll
    for (int mf = 0; mf < 4; ++mf) {
        #pragma unroll
        for (int nf = 0; nf < 4; ++nf) {
            int row = m0 + wm * 64 + mf * 16 + rl;
            int col = n0 + wn * 64 + nf * 16 + cl;
            #pragma unroll
            for (int r2 = 0; r2 < 4; ++r2)
                atomicAdd(&out[(size_t)(row + r2) * OUT_DIM + col], acc[mf][nf][r2]);
        }
    }
}

// ---------------------------------------------------------------------------
extern "C" void kernel_launch(void* const* d_in, const int* in_sizes, int n_in,
                              void* d_out, int out_size, void* d_ws, size_t ws_size,
                              hipStream_t stream) {
    const float* x      = (const float*)d_in[0];   // [4096,256] f32
    const float* coeffs = (const float*)d_in[1];   // [2,256,256,32] f32
    const float* bias   = (const float*)d_in[2];   // [1,256] f32
    float* out = (float*)d_out;                    // [4096,256] f32
    __hip_bfloat16* bmat = (__hip_bfloat16*)d_ws;  // needs 8 MiB

    convert_coeffs<<<(OUT_DIM * K_TOTAL) / 256, 256, 0, stream>>>(coeffs, bmat);
    bias_fill<<<(N_ROWS * OUT_DIM) / 256, 256, 0, stream>>>(bias, out);
    fkan_gemm<<<SPLITK * (N_ROWS / BM) * (OUT_DIM / BN), 256, 0, stream>>>(x, bmat, out);
}

// Round 4
// 127.834 us; speedup vs baseline: 1.1268x; 1.1268x over previous
//
#include <hip/hip_runtime.h>
#include <hip/hip_bf16.h>
#include <cstdint>

typedef __attribute__((ext_vector_type(8))) short  short8;   // 8 x bf16 (4 VGPR)
typedef __attribute__((ext_vector_type(4))) float  f32x4;
typedef __attribute__((ext_vector_type(4))) unsigned uint4v;

#define N_ROWS   4096
#define IN_DIM   256
#define OUT_DIM  256
#define K_TOTAL  16384      // IN_DIM * GRIDSZ * 2
#define SPLITK   8
#define KCHUNK   2048       // K_TOTAL / SPLITK
#define BM       128
#define BN       128
#define BK       64
#define STEPS    32         // KCHUNK / BK == #i handled per block

#define BMAT_BYTES   (OUT_DIM * K_TOTAL * 2)            // 8 MiB
#define PART_ELEMS   (N_ROWS * OUT_DIM)                 // 1 Mi f32 per slice
#define WS_NEEDED    (BMAT_BYTES + SPLITK * PART_ELEMS * 4)

// ---------------------------------------------------------------------------
// BmatT[j][k] (bf16), k = i*64 + g*2 + p ; p=0 -> cos coeffs, p=1 -> sin.
// coeffs layout: [2][out][in][grid] fp32. Vectorized: thread = 8 bm elements.
__global__ void convert_coeffs(const float* __restrict__ w,
                               __hip_bfloat16* __restrict__ bm) {
    int gid = blockIdx.x * 256 + threadIdx.x;      // 0 .. 256*256*8-1
    int j   = gid >> 11;
    int rem = gid & 2047;
    int i   = rem >> 3;
    int g4  = rem & 7;                             // group of 4 g values
    const float* s0 = w + ((size_t)(j * 256 + i)) * 32 + g4 * 4;          // p=0
    const float* s1 = s0 + (size_t)OUT_DIM * IN_DIM * 32;                 // p=1
    f32x4 c4 = *(const f32x4*)s0;
    f32x4 sn = *(const f32x4*)s1;
    __hip_bfloat16 o[8];
    #pragma unroll
    for (int q = 0; q < 4; ++q) {
        o[2 * q]     = __float2bfloat16(c4[q]);
        o[2 * q + 1] = __float2bfloat16(sn[q]);
    }
    *(short8*)(bm + (size_t)j * K_TOTAL + i * 64 + g4 * 8) = *(short8*)o;
}

__global__ void bias_fill(const float* __restrict__ bias, float* __restrict__ out) {
    int gid = blockIdx.x * 256 + threadIdx.x;
    out[gid] = bias[gid & (OUT_DIM - 1)];
}

// out = bias + sum_ks partial[ks]  (f32x4 all the way)
__global__ void reduce_out(const float* __restrict__ part,
                           const float* __restrict__ bias,
                           float* __restrict__ out) {
    int gid = blockIdx.x * 256 + threadIdx.x;      // 0 .. 262143
    int idx = gid * 4;
    f32x4 a = *(const f32x4*)&bias[idx & (OUT_DIM - 1)];
    #pragma unroll
    for (int ks = 0; ks < SPLITK; ++ks)
        a += *(const f32x4*)&part[(size_t)ks * PART_ELEMS + idx];
    *(f32x4*)&out[idx] = a;
}

// ---------------------------------------------------------------------------
__device__ __forceinline__ void gld_lds16(const void* g, void* l) {
    // dest is wave-uniform base; HW writes lane*16B.
    __builtin_amdgcn_global_load_lds(
        (const __attribute__((address_space(1))) void*)(uintptr_t)g,
        (__attribute__((address_space(3))) void*)(uintptr_t)l, 16, 0, 0);
}

// round-to-nearest-even f32 -> bf16 (non-NaN inputs), returned in low 16 bits
__device__ __forceinline__ unsigned f2bf(float f) {
    unsigned u = __builtin_bit_cast(unsigned, f);
    return (u + 0x7fffu + ((u >> 16) & 1u)) >> 16;
}

// 256 threads = 4 waves (2x2), wave tile 64x64. LDS 64 KiB -> 2 blocks/CU.
// PART=true: store split-K partials (no atomics); false: atomicAdd into out.
template <bool PART>
__global__ __launch_bounds__(256, 2) void fkan_gemm(const float* __restrict__ x,
                                                    const __hip_bfloat16* __restrict__ bm,
                                                    float* __restrict__ dst) {
    __shared__ float  x_lds[STEPS][BM];    // 16 KiB, transposed: [i_local][m]
    __shared__ short  A_lds[BM * BK];      // 16 KiB, single-buffered, XOR-swizzled
    __shared__ short  B_lds[2][BN * BK];   // 32 KiB, dbuf, swizzle via global src perm

    const int tid  = threadIdx.x;
    const int lane = tid & 63;
    const int wid  = tid >> 6;      // 4 waves
    const int wm   = wid >> 1;      // 0..1 -> 64-row slice
    const int wn   = wid & 1;       // 0..1 -> 64-col slice

    const int bid = blockIdx.x;
    const int ks  = bid & 7;        // k-split; same-ks blocks share an XCD's L2
    const int tt  = bid >> 3;
    const int mb  = tt >> 1;
    const int nb  = tt & 1;
    const int m0  = mb * BM;
    const int n0  = nb * BN;
    const int i0  = ks * STEPS;
    const int kbase = ks * KCHUNK;

    auto stage_B = [&](int s, int buf) {
        int kg = kbase + s * BK;
        #pragma unroll
        for (int r = 0; r < 4; ++r) {
            int jl = wid * 32 + r * 8 + (lane >> 3);     // LDS row this lane fills
            int cg = (lane & 7) ^ (jl & 7);              // inverse-swizzled src chunk
            const __hip_bfloat16* src = bm + (size_t)(n0 + jl) * K_TOTAL + kg + cg * 8;
            gld_lds16(src, &B_lds[buf][(wid * 32 + r * 8) * BK]);
        }
    };

    const int am = tid & 127;   // A-gen: row this thread generates
    const int ah = tid >> 7;    // A-gen: half (16 multipliers each)

    auto gen_A = [&](int s) {
        float xv = x_lds[s][am];
        float c1, s1; __sincosf(xv, &s1, &c1);                          // cis(x)
        float cg, sg; __sincosf((float)(16 * ah + 1) * xv, &sg, &cg);   // cis((16h+1)x)
        unsigned pk[16];
        #pragma unroll
        for (int e = 0; e < 16; ++e) {
            pk[e] = f2bf(cg) | (f2bf(sg) << 16);         // even k=cos, odd k=sin
            float cn = cg * c1 - sg * s1;                // cis((g+1)x)=cis(gx)cis(x)
            sg = sg * c1 + cg * s1;
            cg = cn;
        }
        int base = am * BK;
        #pragma unroll
        for (int q = 0; q < 4; ++q) {
            uint4v w = {pk[4 * q], pk[4 * q + 1], pk[4 * q + 2], pk[4 * q + 3]};
            *(uint4v*)&A_lds[base + (((4 * ah + q) ^ (am & 7)) << 3)] = w;
        }
    };

    f32x4 acc[4][4];
    #pragma unroll
    for (int a = 0; a < 4; ++a)
        #pragma unroll
        for (int b = 0; b < 4; ++b) acc[a][b] = (f32x4){0.f, 0.f, 0.f, 0.f};

    auto compute = [&](int buf) {
        const int rA = lane & 15;
        const int cA = lane >> 4;
        #pragma unroll
        for (int kf = 0; kf < 2; ++kf) {
            short8 af[4], bf[4];
            #pragma unroll
            for (int mf = 0; mf < 4; ++mf) {
                int row = wm * 64 + mf * 16 + rA;
                int ch  = (kf * 4 + cA) ^ (rA & 7);
                af[mf] = *(const short8*)&A_lds[row * BK + ch * 8];
            }
            #pragma unroll
            for (int nf = 0; nf < 4; ++nf) {
                int row = wn * 64 + nf * 16 + rA;
                int ch  = (kf * 4 + cA) ^ (rA & 7);
                bf[nf] = *(const short8*)&B_lds[buf][row * BK + ch * 8];
            }
            #pragma unroll
            for (int mf = 0; mf < 4; ++mf)
                #pragma unroll
                for (int nf = 0; nf < 4; ++nf)
                    acc[mf][nf] = __builtin_amdgcn_mfma_f32_16x16x32_bf16(
                        af[mf], bf[nf], acc[mf][nf], 0, 0, 0);
        }
    };

    // ---- prologue: issue B(0), stage x panel, gen A(0) ----
    stage_B(0, 0);
    #pragma unroll
    for (int s2 = 0; s2 < 4; ++s2) {
        int slot = tid + s2 * 256;              // 1024 float4 slots
        int m  = slot >> 3;
        int c4 = slot & 7;
        f32x4 xv = *(const f32x4*)&x[(size_t)(m0 + m) * IN_DIM + i0 + c4 * 4];
        #pragma unroll
        for (int q = 0; q < 4; ++q) x_lds[c4 * 4 + q][m] = xv[q];
    }
    __syncthreads();        // x visible (also drains B(0) DMA)
    gen_A(0);

    int cur = 0;
    for (int s = 0; s < STEPS; ++s) {
        __syncthreads();                                // A[s] written, B[cur] landed
        if (s + 1 < STEPS) stage_B(s + 1, cur ^ 1);     // issue early, drains next iter
        compute(cur);
        __syncthreads();                                // all waves done reading A[s]
        if (s + 1 < STEPS) gen_A(s + 1);
        cur ^= 1;
    }

    // epilogue: C/D layout col=lane&15, row=(lane>>4)*4+reg (m89-verified)
    const int cl = lane & 15;
    const int rl = (lane >> 4) * 4;
    float* base = PART ? dst + (size_t)ks * PART_ELEMS : dst;
    #pragma unroll
    for (int mf = 0; mf < 4; ++mf) {
        #pragma unroll
        for (int nf = 0; nf < 4; ++nf) {
            int row = m0 + wm * 64 + mf * 16 + rl;
            int col = n0 + wn * 64 + nf * 16 + cl;
            #pragma unroll
            for (int r2 = 0; r2 < 4; ++r2) {
                if (PART)
                    base[(size_t)(row + r2) * OUT_DIM + col] = acc[mf][nf][r2];
                else
                    atomicAdd(&base[(size_t)(row + r2) * OUT_DIM + col], acc[mf][nf][r2]);
            }
        }
    }
}

// ---------------------------------------------------------------------------
extern "C" void kernel_launch(void* const* d_in, const int* in_sizes, int n_in,
                              void* d_out, int out_size, void* d_ws, size_t ws_size,
                              hipStream_t stream) {
    const float* x      = (const float*)d_in[0];   // [4096,256] f32
    const float* coeffs = (const float*)d_in[1];   // [2,256,256,32] f32
    const float* bias   = (const float*)d_in[2];   // [1,256] f32
    float* out = (float*)d_out;                    // [4096,256] f32
    __hip_bfloat16* bmat = (__hip_bfloat16*)d_ws;  // 8 MiB
    float* part = (float*)((char*)d_ws + BMAT_BYTES);  // 32 MiB split-K partials

    convert_coeffs<<<(OUT_DIM * IN_DIM * 8) / 256, 256, 0, stream>>>(coeffs, bmat);

    const int grid = SPLITK * (N_ROWS / BM) * (OUT_DIM / BN);
    if (ws_size >= (size_t)WS_NEEDED) {
        fkan_gemm<true><<<grid, 256, 0, stream>>>(x, bmat, part);
        reduce_out<<<PART_ELEMS / 4 / 256, 256, 0, stream>>>(part, bias, out);
    } else {
        bias_fill<<<(N_ROWS * OUT_DIM) / 256, 256, 0, stream>>>(bias, out);
        fkan_gemm<false><<<grid, 256, 0, stream>>>(x, bmat, out);
    }
}

// Round 6
// 118.898 us; speedup vs baseline: 1.2114x; 1.0751x over previous
//
#include <hip/hip_runtime.h>
#include <hip/hip_bf16.h>
#include <cstdint>

typedef __attribute__((ext_vector_type(8))) short  short8;   // 8 x bf16 (4 VGPR)
typedef __attribute__((ext_vector_type(4))) float  f32x4;
typedef __attribute__((ext_vector_type(4))) unsigned uint4v;

#define N_ROWS   4096
#define IN_DIM   256
#define OUT_DIM  256
#define K_TOTAL  16384      // IN_DIM * GRIDSZ * 2
#define SPLITK   8
#define KCHUNK   2048       // K_TOTAL / SPLITK
#define BM       128
#define BN       128
#define BK       64
#define STEPS    32         // KCHUNK / BK == #i handled per block

#define BMAT_BYTES   (OUT_DIM * K_TOTAL * 2)            // 8 MiB
#define PART_ELEMS   (N_ROWS * OUT_DIM)                 // 1 Mi f32 per slice
#define WS_NEEDED    (BMAT_BYTES + SPLITK * PART_ELEMS * 4)

// ---------------------------------------------------------------------------
// BmatT[j][k] (bf16), k = i*64 + g*2 + p ; p=0 -> cos coeffs, p=1 -> sin.
// coeffs layout: [2][out][in][grid] fp32. Vectorized: thread = 8 bm elements.
__global__ void convert_coeffs(const float* __restrict__ w,
                               __hip_bfloat16* __restrict__ bm) {
    int gid = blockIdx.x * 256 + threadIdx.x;      // 0 .. 256*256*8-1
    int j   = gid >> 11;
    int rem = gid & 2047;
    int i   = rem >> 3;
    int g4  = rem & 7;                             // group of 4 g values
    const float* s0 = w + ((size_t)(j * 256 + i)) * 32 + g4 * 4;          // p=0
    const float* s1 = s0 + (size_t)OUT_DIM * IN_DIM * 32;                 // p=1
    f32x4 c4 = *(const f32x4*)s0;
    f32x4 sn = *(const f32x4*)s1;
    __hip_bfloat16 o[8];
    #pragma unroll
    for (int q = 0; q < 4; ++q) {
        o[2 * q]     = __float2bfloat16(c4[q]);
        o[2 * q + 1] = __float2bfloat16(sn[q]);
    }
    *(short8*)(bm + (size_t)j * K_TOTAL + i * 64 + g4 * 8) = *(short8*)o;
}

__global__ void bias_fill(const float* __restrict__ bias, float* __restrict__ out) {
    int gid = blockIdx.x * 256 + threadIdx.x;
    out[gid] = bias[gid & (OUT_DIM - 1)];
}

// out = bias + sum_ks partial[ks]  (f32x4 all the way)
__global__ void reduce_out(const float* __restrict__ part,
                           const float* __restrict__ bias,
                           float* __restrict__ out) {
    int gid = blockIdx.x * 256 + threadIdx.x;      // 0 .. 262143
    int idx = gid * 4;
    f32x4 a = *(const f32x4*)&bias[idx & (OUT_DIM - 1)];
    #pragma unroll
    for (int ks = 0; ks < SPLITK; ++ks)
        a += *(const f32x4*)&part[(size_t)ks * PART_ELEMS + idx];
    *(f32x4*)&out[idx] = a;
}

// ---------------------------------------------------------------------------
__device__ __forceinline__ void gld_lds16(const void* g, void* l) {
    // dest is wave-uniform base; HW writes lane*16B.
    __builtin_amdgcn_global_load_lds(
        (const __attribute__((address_space(1))) void*)(uintptr_t)g,
        (__attribute__((address_space(3))) void*)(uintptr_t)l, 16, 0, 0);
}

// pack (c,s) -> one u32 of 2 bf16 (RNE); compiler lowers to v_cvt_pk_bf16_f32
__device__ __forceinline__ unsigned packbf(float c, float s) {
    float2 f2; f2.x = c; f2.y = s;
    __hip_bfloat162 pb = __float22bfloat162_rn(f2);
    unsigned u; __builtin_memcpy(&u, &pb, 4);
    return u;
}

// 256 threads = 4 waves (2x2), wave tile 64x64. LDS 64 KiB -> 2 blocks/CU.
// PART=true: store split-K partials (no atomics); false: atomicAdd into out.
template <bool PART>
__global__ __launch_bounds__(256, 2) void fkan_gemm(const float* __restrict__ x,
                                                    const __hip_bfloat16* __restrict__ bm,
                                                    float* __restrict__ dst) {
    __shared__ float  x_lds[STEPS][BM];    // 16 KiB, transposed: [i_local][m]
    __shared__ short  A_lds[BM * BK];      // 16 KiB, single-buffered, XOR-swizzled
    __shared__ short  B_lds[2][BN * BK];   // 32 KiB, dbuf, swizzle via global src perm

    const int tid  = threadIdx.x;
    const int lane = tid & 63;
    const int wid  = tid >> 6;      // 4 waves
    const int wm   = wid >> 1;      // 0..1 -> 64-row slice
    const int wn   = wid & 1;       // 0..1 -> 64-col slice

    const int bid = blockIdx.x;
    const int ks  = bid & 7;        // k-split; same-ks blocks share an XCD's L2
    const int tt  = bid >> 3;
    const int mb  = tt >> 1;
    const int nb  = tt & 1;
    const int m0  = mb * BM;
    const int n0  = nb * BN;
    const int i0  = ks * STEPS;
    const int kbase = ks * KCHUNK;

    auto stage_B = [&](int s, int buf) {
        int kg = kbase + s * BK;
        #pragma unroll
        for (int r = 0; r < 4; ++r) {
            int jl = wid * 32 + r * 8 + (lane >> 3);     // LDS row this lane fills
            int cg = (lane & 7) ^ (jl & 7);              // inverse-swizzled src chunk
            const __hip_bfloat16* src = bm + (size_t)(n0 + jl) * K_TOTAL + kg + cg * 8;
            gld_lds16(src, &B_lds[buf][(wid * 32 + r * 8) * BK]);
        }
    };

    const int am = tid & 127;   // A-gen: row this thread generates
    const int ah = tid >> 7;    // A-gen: half (16 multipliers each)

    // native transcendentals: v_sin_f32(t) = sin(2*pi*t), fract-reduced.
    auto gen_A = [&](int s) {
        float xv = x_lds[s][am];
        float t  = xv * 0.15915494309189535f;            // x / 2pi (revolutions)
        float tb = __builtin_amdgcn_fractf(t);
        float s1 = __builtin_amdgcn_sinf(tb);            // sin(x)
        float c1 = __builtin_amdgcn_cosf(tb);            // cos(x)
        float tg = (float)(16 * ah + 1) * t;
        float tf = __builtin_amdgcn_fractf(tg);
        float sg = __builtin_amdgcn_sinf(tf);            // sin((16h+1)x)
        float cg = __builtin_amdgcn_cosf(tf);            // cos((16h+1)x)
        unsigned pk[16];
        #pragma unroll
        for (int e = 0; e < 16; ++e) {
            pk[e] = packbf(cg, sg);                      // even k=cos, odd k=sin
            float cn = __builtin_fmaf(cg, c1, -(sg * s1));   // cis((g+1)x)=cis(gx)cis(x)
            sg       = __builtin_fmaf(sg, c1,  (cg * s1));
            cg = cn;
        }
        int base = am * BK;
        #pragma unroll
        for (int q = 0; q < 4; ++q) {
            uint4v w = {pk[4 * q], pk[4 * q + 1], pk[4 * q + 2], pk[4 * q + 3]};
            *(uint4v*)&A_lds[base + (((4 * ah + q) ^ (am & 7)) << 3)] = w;
        }
    };

    f32x4 acc[4][4];
    #pragma unroll
    for (int a = 0; a < 4; ++a)
        #pragma unroll
        for (int b = 0; b < 4; ++b) acc[a][b] = (f32x4){0.f, 0.f, 0.f, 0.f};

    auto compute = [&](int buf) {
        const int rA = lane & 15;
        const int cA = lane >> 4;
        #pragma unroll
        for (int kf = 0; kf < 2; ++kf) {
            short8 af[4], bf[4];
            #pragma unroll
            for (int mf = 0; mf < 4; ++mf) {
                int row = wm * 64 + mf * 16 + rA;
                int ch  = (kf * 4 + cA) ^ (rA & 7);
                af[mf] = *(const short8*)&A_lds[row * BK + ch * 8];
            }
            #pragma unroll
            for (int nf = 0; nf < 4; ++nf) {
                int row = wn * 64 + nf * 16 + rA;
                int ch  = (kf * 4 + cA) ^ (rA & 7);
                bf[nf] = *(const short8*)&B_lds[buf][row * BK + ch * 8];
            }
            #pragma unroll
            for (int mf = 0; mf < 4; ++mf)
                #pragma unroll
                for (int nf = 0; nf < 4; ++nf)
                    acc[mf][nf] = __builtin_amdgcn_mfma_f32_16x16x32_bf16(
                        af[mf], bf[nf], acc[mf][nf], 0, 0, 0);
        }
    };

    // ---- prologue: issue B(0), stage x panel, gen A(0) ----
    stage_B(0, 0);
    #pragma unroll
    for (int s2 = 0; s2 < 4; ++s2) {
        int slot = tid + s2 * 256;              // 1024 float4 slots
        int m  = slot >> 3;
        int c4 = slot & 7;
        f32x4 xv = *(const f32x4*)&x[(size_t)(m0 + m) * IN_DIM + i0 + c4 * 4];
        #pragma unroll
        for (int q = 0; q < 4; ++q) x_lds[c4 * 4 + q][m] = xv[q];
    }
    __syncthreads();        // x visible (also drains B(0) DMA)
    gen_A(0);

    int cur = 0;
    for (int s = 0; s < STEPS; ++s) {
        __syncthreads();                                // A[s] written, B[cur] landed
        if (s + 1 < STEPS) stage_B(s + 1, cur ^ 1);     // issue early, drains next iter
        compute(cur);
        __syncthreads();                                // all waves done reading A[s]
        if (s + 1 < STEPS) gen_A(s + 1);
        cur ^= 1;
    }

    // epilogue: C/D layout col=lane&15, row=(lane>>4)*4+reg (m89-verified)
    const int cl = lane & 15;
    const int rl = (lane >> 4) * 4;
    float* base = PART ? dst + (size_t)ks * PART_ELEMS : dst;
    #pragma unroll
    for (int mf = 0; mf < 4; ++mf) {
        #pragma unroll
        for (int nf = 0; nf < 4; ++nf) {
            int row = m0 + wm * 64 + mf * 16 + rl;
            int col = n0 + wn * 64 + nf * 16 + cl;
            #pragma unroll
            for (int r2 = 0; r2 < 4; ++r2) {
                if (PART)
                    base[(size_t)(row + r2) * OUT_DIM + col] = acc[mf][nf][r2];
                else
                    atomicAdd(&base[(size_t)(row + r2) * OUT_DIM + col], acc[mf][nf][r2]);
            }
        }
    }
}

// ---------------------------------------------------------------------------
extern "C" void kernel_launch(void* const* d_in, const int* in_sizes, int n_in,
                              void* d_out, int out_size, void* d_ws, size_t ws_size,
                              hipStream_t stream) {
    const float* x      = (const float*)d_in[0];   // [4096,256] f32
    const float* coeffs = (const float*)d_in[1];   // [2,256,256,32] f32
    const float* bias   = (const float*)d_in[2];   // [1,256] f32
    float* out = (float*)d_out;                    // [4096,256] f32
    __hip_bfloat16* bmat = (__hip_bfloat16*)d_ws;  // 8 MiB
    float* part = (float*)((char*)d_ws + BMAT_BYTES);  // 32 MiB split-K partials

    convert_coeffs<<<(OUT_DIM * IN_DIM * 8) / 256, 256, 0, stream>>>(coeffs, bmat);

    const int grid = SPLITK * (N_ROWS / BM) * (OUT_DIM / BN);
    if (ws_size >= (size_t)WS_NEEDED) {
        fkan_gemm<true><<<grid, 256, 0, stream>>>(x, bmat, part);
        reduce_out<<<PART_ELEMS / 4 / 256, 256, 0, stream>>>(part, bias, out);
    } else {
        bias_fill<<<(N_ROWS * OUT_DIM) / 256, 256, 0, stream>>>(bias, out);
        fkan_gemm<false><<<grid, 256, 0, stream>>>(x, bmat, out);
    }
}